// Round 1
// baseline (67.325 us; speedup 1.0000x reference)
//
#include <hip/hip_runtime.h>

#define BB 8
#define NN 2048
#define FIN 256
#define FOUT 128

__device__ __forceinline__ float leaky(float x) { return fmaxf(x, 0.2f * x); }

// ---------------- Kernel A: Wh[b,n,o] = sum_f h[b,n,f] * W[f,o] ----------------
// 512 blocks, 256 threads. Tile: 32 rows x 128 cols. h tile staged in LDS (32KB).
__global__ __launch_bounds__(256) void k_gemm(const float* __restrict__ h,
                                              const float* __restrict__ W,
                                              float* __restrict__ Wh) {
    __shared__ float hs[32 * FIN];  // 32 KB
    const int tid = threadIdx.x;
    const int blk = blockIdx.x;
    const int b = blk >> 6;            // / (N/32)
    const int row0 = (blk & 63) << 5;  // * 32

    const float4* hsrc = (const float4*)(h + ((size_t)(b * NN + row0)) * FIN);
    float4* hsv = (float4*)hs;
#pragma unroll
    for (int t = 0; t < 8; ++t) hsv[tid + t * 256] = hsrc[tid + t * 256];
    __syncthreads();

    const int ot = tid & 31;  // o-group: cols ot*4 .. ot*4+3
    const int rt = tid >> 5;  // 0..7: rows rt*4 .. rt*4+3
    float acc[4][4] = {};
    const float4* Wv = (const float4*)W;  // W[f][o] at f*32 + o/4 (float4 units)

    for (int f0 = 0; f0 < FIN; f0 += 4) {
        const float4 w0 = Wv[(f0 + 0) * 32 + ot];
        const float4 w1 = Wv[(f0 + 1) * 32 + ot];
        const float4 w2 = Wv[(f0 + 2) * 32 + ot];
        const float4 w3 = Wv[(f0 + 3) * 32 + ot];
#pragma unroll
        for (int rr = 0; rr < 4; ++rr) {
            const int r = rt * 4 + rr;
            const float4 hv = *((const float4*)&hs[r * FIN + f0]);
            acc[rr][0] += hv.x * w0.x + hv.y * w1.x + hv.z * w2.x + hv.w * w3.x;
            acc[rr][1] += hv.x * w0.y + hv.y * w1.y + hv.z * w2.y + hv.w * w3.y;
            acc[rr][2] += hv.x * w0.z + hv.y * w1.z + hv.z * w2.z + hv.w * w3.z;
            acc[rr][3] += hv.x * w0.w + hv.y * w1.w + hv.z * w2.w + hv.w * w3.w;
        }
    }

#pragma unroll
    for (int rr = 0; rr < 4; ++rr) {
        const int r = rt * 4 + rr;
        float4 v = make_float4(acc[rr][0], acc[rr][1], acc[rr][2], acc[rr][3]);
        ((float4*)(Wh + ((size_t)(b * NN + row0 + r)) * FOUT))[ot] = v;
    }
}

// ---------------- Kernel B: ei = Wh@a1, ej = Wh@a2 (wave per row) ----------------
__global__ __launch_bounds__(256) void k_ei_ej(const float* __restrict__ Wh,
                                               const float* __restrict__ a,
                                               float* __restrict__ ei,
                                               float* __restrict__ ej) {
    const int w = blockIdx.x * 4 + (threadIdx.x >> 6);  // global row in [0, B*N)
    const int lane = threadIdx.x & 63;
    const float2 v = ((const float2*)(Wh + (size_t)w * FOUT))[lane];
    const int o = lane * 2;
    float s1 = v.x * a[o] + v.y * a[o + 1];
    float s2 = v.x * a[FOUT + o] + v.y * a[FOUT + o + 1];
#pragma unroll
    for (int off = 32; off > 0; off >>= 1) {
        s1 += __shfl_xor(s1, off);
        s2 += __shfl_xor(s2, off);
    }
    if (lane == 0) { ei[w] = s1; ej[w] = s2; }
}

// ---------------- Kernel C: per-batch max of ej ----------------
__global__ __launch_bounds__(256) void k_max(const float* __restrict__ ej,
                                             float* __restrict__ M) {
    __shared__ float red[4];
    const int b = blockIdx.x, tid = threadIdx.x;
    float m = -1e30f;
#pragma unroll
    for (int t = 0; t < 8; ++t) m = fmaxf(m, ej[b * NN + tid + t * 256]);
#pragma unroll
    for (int off = 32; off > 0; off >>= 1) m = fmaxf(m, __shfl_xor(m, off));
    if ((tid & 63) == 0) red[tid >> 6] = m;
    __syncthreads();
    if (tid == 0) M[b] = fmaxf(fmaxf(red[0], red[1]), fmaxf(red[2], red[3]));
}

// ---------------- Kernel D: linv[i] = 1 / sum_j exp(leaky(ei+ej) - m_i) ----------------
// wave per row i. m_i = leaky(ei + max_j ej) since leaky is monotone increasing.
__global__ __launch_bounds__(256) void k_row(const float* __restrict__ ei,
                                             const float* __restrict__ ej,
                                             const float* __restrict__ M,
                                             float* __restrict__ linv) {
    const int w = blockIdx.x * 4 + (threadIdx.x >> 6);
    const int lane = threadIdx.x & 63;
    const int b = w >> 11;
    const float eiv = ei[w];
    const float m = leaky(eiv + M[b]);
    const float* ejb = ej + ((size_t)b << 11);
    float s = 0.f;
#pragma unroll 4
    for (int t = 0; t < 32; ++t) {
        const float x = leaky(eiv + ejb[t * 64 + lane]);
        s += __expf(x - m);
    }
#pragma unroll
    for (int off = 32; off > 0; off >>= 1) s += __shfl_xor(s, off);
    if (lane == 0) linv[w] = 1.0f / s;
}

// ---------------- Kernel E: c[j] = (1/N) sum_i exp(leaky(ei+ej) - m_i) * linv[i] ----------------
__global__ __launch_bounds__(256) void k_col(const float* __restrict__ ei,
                                             const float* __restrict__ ej,
                                             const float* __restrict__ M,
                                             const float* __restrict__ linv,
                                             float* __restrict__ c) {
    const int w = blockIdx.x * 4 + (threadIdx.x >> 6);
    const int lane = threadIdx.x & 63;
    const int b = w >> 11;
    const float ejv = ej[w];
    const float mb = M[b];
    const float* eib = ei + ((size_t)b << 11);
    const float* lb = linv + ((size_t)b << 11);
    float s = 0.f;
#pragma unroll 4
    for (int t = 0; t < 32; ++t) {
        const float eiv = eib[t * 64 + lane];
        const float m = leaky(eiv + mb);
        const float x = leaky(eiv + ejv);
        s += __expf(x - m) * lb[t * 64 + lane];
    }
#pragma unroll
    for (int off = 32; off > 0; off >>= 1) s += __shfl_xor(s, off);
    if (lane == 0) c[w] = s * (1.0f / NN);
}

// ---------------- Kernel F: out[b,o] += sum_{j in chunk} c[j] * Wh[b,j,o] ----------------
__global__ __launch_bounds__(256) void k_out(const float* __restrict__ Wh,
                                             const float* __restrict__ c,
                                             float* __restrict__ out) {
    const int b = blockIdx.y;
    const int j0 = blockIdx.x * 128;
    const int o = threadIdx.x & 127;
    const int js = threadIdx.x >> 7;
    const float* cb = c + ((size_t)b << 11);
    float acc = 0.f;
#pragma unroll 4
    for (int t = 0; t < 64; ++t) {
        const int j = j0 + js * 64 + t;
        acc += cb[j] * Wh[(((size_t)b << 11) + j) * FOUT + o];
    }
    atomicAdd(&out[b * FOUT + o], acc);
}

extern "C" void kernel_launch(void* const* d_in, const int* in_sizes, int n_in,
                              void* d_out, int out_size, void* d_ws, size_t ws_size,
                              hipStream_t stream) {
    const float* h = (const float*)d_in[0];
    const float* W = (const float*)d_in[1];
    const float* a = (const float*)d_in[2];
    float* out = (float*)d_out;

    float* ws = (float*)d_ws;
    float* Wh = ws;                                 // B*N*FOUT = 2,097,152 floats
    float* ei = Wh + (size_t)BB * NN * FOUT;        // 16384
    float* ej = ei + BB * NN;                       // 16384
    float* linv = ej + BB * NN;                     // 16384
    float* c = linv + BB * NN;                      // 16384
    float* M = c + BB * NN;                         // 8

    hipMemsetAsync(d_out, 0, (size_t)out_size * sizeof(float), stream);

    k_gemm<<<512, 256, 0, stream>>>(h, W, Wh);
    k_ei_ej<<<4096, 256, 0, stream>>>(Wh, a, ei, ej);
    k_max<<<BB, 256, 0, stream>>>(ej, M);
    k_row<<<4096, 256, 0, stream>>>(ei, ej, M, linv);
    k_col<<<4096, 256, 0, stream>>>(ei, ej, M, linv, c);
    dim3 gF(16, BB);
    k_out<<<gF, 256, 0, stream>>>(Wh, c, out);
}

// Round 2
// 61.763 us; speedup vs baseline: 1.0900x; 1.0900x over previous
//
#include <hip/hip_runtime.h>

#define BB 8
#define NN 2048
#define FIN 256
#define FOUT 128

__device__ __forceinline__ float leaky(float x) { return fmaxf(x, 0.2f * x); }

// ---------------- Kernel A: Wh = h@W  +  ei/ej epilogue ----------------
// 512 blocks, 256 threads. Tile: 32 rows x 128 cols. h tile staged in LDS (32KB).
// Epilogue: ei[r] = Wh[r,:]@a1, ej[r] = Wh[r,:]@a2 via half-wave reduction.
__global__ __launch_bounds__(256) void k_gemm(const float* __restrict__ h,
                                              const float* __restrict__ W,
                                              const float* __restrict__ a,
                                              float* __restrict__ Wh,
                                              float* __restrict__ ei,
                                              float* __restrict__ ej) {
    __shared__ float hs[32 * FIN];  // 32 KB
    const int tid = threadIdx.x;
    const int blk = blockIdx.x;
    const int b = blk >> 6;            // / (N/32)
    const int row0 = (blk & 63) << 5;  // * 32

    const float4* hsrc = (const float4*)(h + ((size_t)(b * NN + row0)) * FIN);
    float4* hsv = (float4*)hs;
#pragma unroll
    for (int t = 0; t < 8; ++t) hsv[tid + t * 256] = hsrc[tid + t * 256];
    __syncthreads();

    const int ot = tid & 31;  // o-group: cols ot*4 .. ot*4+3
    const int rt = tid >> 5;  // 0..7: rows rt*4 .. rt*4+3
    float acc[4][4] = {};
    const float4* Wv = (const float4*)W;  // W[f][o] at f*32 + o/4 (float4 units)

    for (int f0 = 0; f0 < FIN; f0 += 4) {
        const float4 w0 = Wv[(f0 + 0) * 32 + ot];
        const float4 w1 = Wv[(f0 + 1) * 32 + ot];
        const float4 w2 = Wv[(f0 + 2) * 32 + ot];
        const float4 w3 = Wv[(f0 + 3) * 32 + ot];
#pragma unroll
        for (int rr = 0; rr < 4; ++rr) {
            const int r = rt * 4 + rr;
            const float4 hv = *((const float4*)&hs[r * FIN + f0]);
            acc[rr][0] += hv.x * w0.x + hv.y * w1.x + hv.z * w2.x + hv.w * w3.x;
            acc[rr][1] += hv.x * w0.y + hv.y * w1.y + hv.z * w2.y + hv.w * w3.y;
            acc[rr][2] += hv.x * w0.z + hv.y * w1.z + hv.z * w2.z + hv.w * w3.z;
            acc[rr][3] += hv.x * w0.w + hv.y * w1.w + hv.z * w2.w + hv.w * w3.w;
        }
    }

#pragma unroll
    for (int rr = 0; rr < 4; ++rr) {
        const int r = rt * 4 + rr;
        float4 v = make_float4(acc[rr][0], acc[rr][1], acc[rr][2], acc[rr][3]);
        ((float4*)(Wh + ((size_t)(b * NN + row0 + r)) * FOUT))[ot] = v;
    }

    // ---- epilogue: ei/ej for this block's 32 rows ----
    const float4 a1v = ((const float4*)a)[ot];       // a1[ot*4 .. +3]
    const float4 a2v = ((const float4*)a)[32 + ot];  // a2[ot*4 .. +3]
#pragma unroll
    for (int rr = 0; rr < 4; ++rr) {
        float s1 = acc[rr][0] * a1v.x + acc[rr][1] * a1v.y + acc[rr][2] * a1v.z + acc[rr][3] * a1v.w;
        float s2 = acc[rr][0] * a2v.x + acc[rr][1] * a2v.y + acc[rr][2] * a2v.z + acc[rr][3] * a2v.w;
#pragma unroll
        for (int off = 16; off > 0; off >>= 1) {  // reduce across 32 ot-lanes (half-wave)
            s1 += __shfl_xor(s1, off);
            s2 += __shfl_xor(s2, off);
        }
        if ((tid & 31) == 0) {
            const int g = b * NN + row0 + rt * 4 + rr;
            ei[g] = s1;
            ej[g] = s2;
        }
    }
}

// ---------------- Kernel B: row pass — linv[i] = 1/sum_j exp(leaky(ei+ej)-m_i) ----------------
// 1024 blocks x 1024 threads; 16 rows per block (wave per row); per-block batch max from ej.
__global__ __launch_bounds__(1024) void k_row(const float* __restrict__ ei,
                                              const float* __restrict__ ej,
                                              float* __restrict__ linv) {
    __shared__ float red[16];
    __shared__ float sM;
    const int tid = threadIdx.x;
    const int bid = blockIdx.x;
    const int b = bid >> 7;  // 128 blocks per batch
    const float* ejb = ej + ((size_t)b << 11);

    // per-block batch max of ej
    float m = fmaxf(ejb[tid], ejb[tid + 1024]);
#pragma unroll
    for (int off = 32; off > 0; off >>= 1) m = fmaxf(m, __shfl_xor(m, off));
    if ((tid & 63) == 0) red[tid >> 6] = m;
    __syncthreads();
    if (tid == 0) {
        float mm = red[0];
#pragma unroll
        for (int k = 1; k < 16; ++k) mm = fmaxf(mm, red[k]);
        sM = mm;
    }
    __syncthreads();
    const float Mb = sM;

    const int w = tid >> 6, lane = tid & 63;
    const int i = (bid << 4) + w;  // global row
    const float eiv = ei[i];
    const float mi = leaky(eiv + Mb);
    float s = 0.f;
#pragma unroll 4
    for (int t = 0; t < 32; ++t) s += __expf(leaky(eiv + ejb[t * 64 + lane]) - mi);
#pragma unroll
    for (int off = 32; off > 0; off >>= 1) s += __shfl_xor(s, off);
    if (lane == 0) linv[i] = 1.0f / s;
}

// ---------------- Kernel C: col pass + output accumulation ----------------
// 1024 blocks x 1024 threads; 16 j per block (wave per j).
// c_j = (1/N) sum_i exp(leaky(ei+ej)-m_i)*linv[i]; then out[b,:] += sum_j c_j*Wh[j,:].
__global__ __launch_bounds__(1024) void k_col(const float* __restrict__ Wh,
                                              const float* __restrict__ ei,
                                              const float* __restrict__ ej,
                                              const float* __restrict__ linv,
                                              float* __restrict__ out) {
    __shared__ float red[16];
    __shared__ float sM;
    __shared__ float cj[16];
    __shared__ float pbuf[8][FOUT];
    const int tid = threadIdx.x;
    const int bid = blockIdx.x;
    const int b = bid >> 7;
    const float* ejb = ej + ((size_t)b << 11);
    const float* eib = ei + ((size_t)b << 11);
    const float* lb = linv + ((size_t)b << 11);

    // per-block batch max of ej
    float m = fmaxf(ejb[tid], ejb[tid + 1024]);
#pragma unroll
    for (int off = 32; off > 0; off >>= 1) m = fmaxf(m, __shfl_xor(m, off));
    if ((tid & 63) == 0) red[tid >> 6] = m;
    __syncthreads();
    if (tid == 0) {
        float mm = red[0];
#pragma unroll
        for (int k = 1; k < 16; ++k) mm = fmaxf(mm, red[k]);
        sM = mm;
    }
    __syncthreads();
    const float Mb = sM;

    const int w = tid >> 6, lane = tid & 63;
    const int jg = (bid << 4) + w;  // global j row
    const float ejv = ej[jg];
    float s = 0.f;
#pragma unroll 4
    for (int t = 0; t < 32; ++t) {
        const float eiv = eib[t * 64 + lane];
        const float mi = leaky(eiv + Mb);
        const float x = leaky(eiv + ejv);
        s += __expf(x - mi) * lb[t * 64 + lane];
    }
#pragma unroll
    for (int off = 32; off > 0; off >>= 1) s += __shfl_xor(s, off);
    if (lane == 0) cj[w] = s * (1.0f / NN);
    __syncthreads();

    // out partial: 16 j rows of this block, all batch b
    const int o = tid & 127;
    const int grp = tid >> 7;  // 0..7, handles j = grp*2, grp*2+1
    const int j0 = (bid << 4) + grp * 2;
    float p = cj[grp * 2] * Wh[(size_t)j0 * FOUT + o] +
              cj[grp * 2 + 1] * Wh[(size_t)(j0 + 1) * FOUT + o];
    pbuf[grp][o] = p;
    __syncthreads();
    if (tid < FOUT) {
        float t0 = 0.f;
#pragma unroll
        for (int k = 0; k < 8; ++k) t0 += pbuf[k][tid];
        atomicAdd(&out[b * FOUT + tid], t0);
    }
}

extern "C" void kernel_launch(void* const* d_in, const int* in_sizes, int n_in,
                              void* d_out, int out_size, void* d_ws, size_t ws_size,
                              hipStream_t stream) {
    const float* h = (const float*)d_in[0];
    const float* W = (const float*)d_in[1];
    const float* a = (const float*)d_in[2];
    float* out = (float*)d_out;

    float* ws = (float*)d_ws;
    float* Wh = ws;                          // B*N*FOUT = 2,097,152 floats
    float* ei = Wh + (size_t)BB * NN * FOUT; // 16384
    float* ej = ei + BB * NN;                // 16384
    float* linv = ej + BB * NN;              // 16384

    hipMemsetAsync(d_out, 0, (size_t)out_size * sizeof(float), stream);

    k_gemm<<<512, 256, 0, stream>>>(h, W, a, Wh, ei, ej);
    k_row<<<1024, 1024, 0, stream>>>(ei, ej, linv);
    k_col<<<1024, 1024, 0, stream>>>(Wh, ei, ej, linv, out);
}

// Round 3
// 47.881 us; speedup vs baseline: 1.4061x; 1.2899x over previous
//
#include <hip/hip_runtime.h>
#include <hip/hip_bf16.h>

#define BB 8
#define NN 2048
#define FIN 256
#define FOUT 128

typedef __attribute__((ext_vector_type(8))) short bf16x8;
typedef __attribute__((ext_vector_type(4))) float f32x4;

__device__ __forceinline__ float leaky(float x) { return fmaxf(x, 0.2f * x); }
__device__ __forceinline__ unsigned short bfu(float f) {
    return __builtin_bit_cast(unsigned short, __float2bfloat16(f));
}
__device__ __forceinline__ bf16x8 as_frag(int4 v) { return __builtin_bit_cast(bf16x8, v); }

// ---------------- Kernel P: Wt[n][k] = bf16(W[k][n]) ; block 8 zeroes out ----------------
__global__ __launch_bounds__(256) void k_prep(const float* __restrict__ W,
                                              unsigned short* __restrict__ Wt,
                                              float* __restrict__ out) {
    if (blockIdx.x == 8) {
        const int i = threadIdx.x;
#pragma unroll
        for (int r = 0; r < 4; ++r) out[i + r * 256] = 0.f;
        return;
    }
    __shared__ float tile[32][129];
    const int kt = blockIdx.x, tid = threadIdx.x;
#pragma unroll 4
    for (int rep = 0; rep < 16; ++rep) {
        const int r = rep * 2 + (tid >> 7), n = tid & 127;
        tile[r][n] = W[(kt * 32 + r) * FOUT + n];
    }
    __syncthreads();
    const int kk = tid & 31, n0 = tid >> 5;
#pragma unroll 4
    for (int rep = 0; rep < 16; ++rep) {
        const int n = rep * 8 + n0;
        Wt[n * FIN + kt * 32 + kk] = bfu(tile[kk][n]);
    }
}

// ---------------- Kernel A: Wh = h@W via bf16 MFMA + ei/ej epilogue ----------------
// 512 blocks x 256 threads (4 waves). Tile 32 rows x 128 cols, full K=256 in LDS.
// LDS: Bs = whole W^T bf16 (64KB, XOR-swizzled rows), As = h tile bf16 (16KB, swizzled).
__global__ __launch_bounds__(256) void k_gemm(const float* __restrict__ h,
                                              const unsigned short* __restrict__ Wt,
                                              const float* __restrict__ a,
                                              float* __restrict__ Wh,
                                              float* __restrict__ ei,
                                              float* __restrict__ ej) {
    __shared__ int4 Bs[4096];  // 64 KB: row n (128), 32 chunks of 16B (256 k * 2B)
    __shared__ int4 As[1024];  // 16 KB: row r (32), 32 chunks; reused as eb[4096] floats
    const int tid = threadIdx.x;
    const int b = blockIdx.x >> 6;
    const int row0 = (blockIdx.x & 63) << 5;

    // stage B: linear copy with XOR swizzle (chunk c of row n -> c ^ (n&7))
    {
        const int4* Bsrc = (const int4*)Wt;
#pragma unroll
        for (int rep = 0; rep < 16; ++rep) {
            const int chunk = rep * 256 + tid;
            const int n = chunk >> 5, c = chunk & 31;
            Bs[n * 32 + (c ^ (n & 7))] = Bsrc[chunk];
        }
    }
    // stage A: h f32 -> bf16, swizzled
    {
        const float4* hsrc = (const float4*)(h + ((size_t)(b * NN + row0)) * FIN);
        const int r = tid >> 3, kc = tid & 7;
        float4 f[8];
#pragma unroll
        for (int j = 0; j < 8; ++j) f[j] = hsrc[r * 64 + kc * 8 + j];
#pragma unroll
        for (int j2 = 0; j2 < 4; ++j2) {
            union { unsigned short u[8]; int4 v; } p;
            const float4 lo = f[j2 * 2], hi = f[j2 * 2 + 1];
            p.u[0] = bfu(lo.x); p.u[1] = bfu(lo.y); p.u[2] = bfu(lo.z); p.u[3] = bfu(lo.w);
            p.u[4] = bfu(hi.x); p.u[5] = bfu(hi.y); p.u[6] = bfu(hi.z); p.u[7] = bfu(hi.w);
            const int c = kc * 4 + j2;
            As[r * 32 + (c ^ (r & 7))] = p.v;
        }
    }
    __syncthreads();

    const int w = tid >> 6, l = tid & 63;
    const int lr = l & 15, kg = l >> 4;
    f32x4 acc[2][2] = {};
#pragma unroll
    for (int kk = 0; kk < 8; ++kk) {
        const int ca = kk * 4 + kg;  // k = ca*8 = kk*32 + kg*8
        const bf16x8 a0 = as_frag(As[lr * 32 + (ca ^ (lr & 7))]);
        const bf16x8 a1 = as_frag(As[(16 + lr) * 32 + (ca ^ (lr & 7))]);
        const int col0 = w * 32 + lr, col1 = col0 + 16;
        const bf16x8 b0 = as_frag(Bs[col0 * 32 + (ca ^ (col0 & 7))]);
        const bf16x8 b1 = as_frag(Bs[col1 * 32 + (ca ^ (col1 & 7))]);
        acc[0][0] = __builtin_amdgcn_mfma_f32_16x16x32_bf16(a0, b0, acc[0][0], 0, 0, 0);
        acc[0][1] = __builtin_amdgcn_mfma_f32_16x16x32_bf16(a0, b1, acc[0][1], 0, 0, 0);
        acc[1][0] = __builtin_amdgcn_mfma_f32_16x16x32_bf16(a1, b0, acc[1][0], 0, 0, 0);
        acc[1][1] = __builtin_amdgcn_mfma_f32_16x16x32_bf16(a1, b1, acc[1][1], 0, 0, 0);
    }

    // Wh write: D row = kg*4+reg (within 16-tile), col = lr
#pragma unroll
    for (int mt = 0; mt < 2; ++mt)
#pragma unroll
        for (int nt = 0; nt < 2; ++nt)
#pragma unroll
            for (int reg = 0; reg < 4; ++reg) {
                const int gr = row0 + mt * 16 + kg * 4 + reg;
                const int gc = w * 32 + nt * 16 + lr;
                Wh[((size_t)(b * NN + gr)) * FOUT + gc] = acc[mt][nt][reg];
            }

    // ei/ej epilogue: per-lane partial dots -> LDS (skewed to avoid bank conflicts) -> reduce
    __syncthreads();  // done reading As
    float* eb = (float*)As;  // [2][32][64]
    const float a1c0 = a[w * 32 + lr], a1c1 = a[w * 32 + 16 + lr];
    const float a2c0 = a[FOUT + w * 32 + lr], a2c1 = a[FOUT + w * 32 + 16 + lr];
    const int idx = w * 16 + lr;
#pragma unroll
    for (int mt = 0; mt < 2; ++mt)
#pragma unroll
        for (int reg = 0; reg < 4; ++reg) {
            const int r = mt * 16 + kg * 4 + reg;
            const float v1 = acc[mt][0][reg] * a1c0 + acc[mt][1][reg] * a1c1;
            const float v2 = acc[mt][0][reg] * a2c0 + acc[mt][1][reg] * a2c1;
            eb[r * 64 + ((idx + r) & 63)] = v1;
            eb[2048 + r * 64 + ((idx + r) & 63)] = v2;
        }
    __syncthreads();
    if (tid < 64) {
        const int s = tid >> 5, r = tid & 31;
        const float* base = eb + s * 2048 + r * 64;
        float t0 = 0.f;
#pragma unroll
        for (int i = 0; i < 64; ++i) t0 += base[(i + r) & 63];
        if (s == 0) ei[b * NN + row0 + r] = t0;
        else        ej[b * NN + row0 + r] = t0;
    }
}

// ---------------- Kernel B: row pass — linv[i] = 1/sum_j exp(leaky(ei+ej)-m_i) ----------------
__global__ __launch_bounds__(1024) void k_row(const float* __restrict__ ei,
                                              const float* __restrict__ ej,
                                              float* __restrict__ linv) {
    __shared__ float red[16];
    __shared__ float sM;
    const int tid = threadIdx.x;
    const int bid = blockIdx.x;
    const int b = bid >> 7;
    const float* ejb = ej + ((size_t)b << 11);

    float m = fmaxf(ejb[tid], ejb[tid + 1024]);
#pragma unroll
    for (int off = 32; off > 0; off >>= 1) m = fmaxf(m, __shfl_xor(m, off));
    if ((tid & 63) == 0) red[tid >> 6] = m;
    __syncthreads();
    if (tid == 0) {
        float mm = red[0];
#pragma unroll
        for (int k = 1; k < 16; ++k) mm = fmaxf(mm, red[k]);
        sM = mm;
    }
    __syncthreads();
    const float Mb = sM;

    const int w = tid >> 6, lane = tid & 63;
    const int i = (bid << 4) + w;
    const float eiv = ei[i];
    const float mi = leaky(eiv + Mb);
    float s = 0.f;
#pragma unroll 4
    for (int t = 0; t < 32; ++t) s += __expf(leaky(eiv + ejb[t * 64 + lane]) - mi);
#pragma unroll
    for (int off = 32; off > 0; off >>= 1) s += __shfl_xor(s, off);
    if (lane == 0) linv[i] = 1.0f / s;
}

// ---------------- Kernel C: col pass + output accumulation ----------------
__global__ __launch_bounds__(1024) void k_col(const float* __restrict__ Wh,
                                              const float* __restrict__ ei,
                                              const float* __restrict__ ej,
                                              const float* __restrict__ linv,
                                              float* __restrict__ out) {
    __shared__ float red[16];
    __shared__ float sM;
    __shared__ float cj[16];
    __shared__ float pbuf[8][FOUT];
    const int tid = threadIdx.x;
    const int bid = blockIdx.x;
    const int b = bid >> 7;
    const float* ejb = ej + ((size_t)b << 11);
    const float* eib = ei + ((size_t)b << 11);
    const float* lb = linv + ((size_t)b << 11);

    float m = fmaxf(ejb[tid], ejb[tid + 1024]);
#pragma unroll
    for (int off = 32; off > 0; off >>= 1) m = fmaxf(m, __shfl_xor(m, off));
    if ((tid & 63) == 0) red[tid >> 6] = m;
    __syncthreads();
    if (tid == 0) {
        float mm = red[0];
#pragma unroll
        for (int k = 1; k < 16; ++k) mm = fmaxf(mm, red[k]);
        sM = mm;
    }
    __syncthreads();
    const float Mb = sM;

    const int w = tid >> 6, lane = tid & 63;
    const int jg = (bid << 4) + w;
    const float ejv = ej[jg];
    float s = 0.f;
#pragma unroll 4
    for (int t = 0; t < 32; ++t) {
        const float eiv = eib[t * 64 + lane];
        const float mi = leaky(eiv + Mb);
        const float x = leaky(eiv + ejv);
        s += __expf(x - mi) * lb[t * 64 + lane];
    }
#pragma unroll
    for (int off = 32; off > 0; off >>= 1) s += __shfl_xor(s, off);
    if (lane == 0) cj[w] = s * (1.0f / NN);
    __syncthreads();

    const int o = tid & 127;
    const int grp = tid >> 7;
    const int j0 = (bid << 4) + grp * 2;
    float p = cj[grp * 2] * Wh[(size_t)j0 * FOUT + o] +
              cj[grp * 2 + 1] * Wh[(size_t)(j0 + 1) * FOUT + o];
    pbuf[grp][o] = p;
    __syncthreads();
    if (tid < FOUT) {
        float t0 = 0.f;
#pragma unroll
        for (int k = 0; k < 8; ++k) t0 += pbuf[k][tid];
        atomicAdd(&out[b * FOUT + tid], t0);
    }
}

extern "C" void kernel_launch(void* const* d_in, const int* in_sizes, int n_in,
                              void* d_out, int out_size, void* d_ws, size_t ws_size,
                              hipStream_t stream) {
    const float* h = (const float*)d_in[0];
    const float* W = (const float*)d_in[1];
    const float* a = (const float*)d_in[2];
    float* out = (float*)d_out;

    float* ws = (float*)d_ws;
    float* Wh = ws;                           // 2,097,152 floats
    float* ei = Wh + (size_t)BB * NN * FOUT;  // 16384
    float* ej = ei + BB * NN;                 // 16384
    float* linv = ej + BB * NN;               // 16384
    unsigned short* Wt = (unsigned short*)(linv + BB * NN);  // 32768 bf16 (64KB)

    k_prep<<<9, 256, 0, stream>>>(W, Wt, out);
    k_gemm<<<512, 256, 0, stream>>>(h, Wt, a, Wh, ei, ej);
    k_row<<<1024, 1024, 0, stream>>>(ei, ej, linv);
    k_col<<<1024, 1024, 0, stream>>>(Wh, ei, ej, linv, out);
}

// Round 4
// 45.961 us; speedup vs baseline: 1.4648x; 1.0418x over previous
//
#include <hip/hip_runtime.h>

#define BB 8
#define NN 2048
#define FIN 256
#define FOUT 128

// ---------------- Kernel P: wa1 = W@a1, wa2 = W@a2; zero g and out ----------------
// 8 blocks x 256 threads. Thread (r, og): partial dot of W row f over 16 cols.
__global__ __launch_bounds__(256) void k_prep(const float* __restrict__ W,
                                              const float* __restrict__ a,
                                              float* __restrict__ wa,  // [2][FIN]
                                              float* __restrict__ g,   // [BB][FIN]
                                              float* __restrict__ out) {
    const int tid = threadIdx.x, blk = blockIdx.x;
    const int gi = blk * 256 + tid;  // 0..2047
    g[gi] = 0.f;
    if (gi < BB * FOUT) out[gi] = 0.f;

    const int f = blk * 32 + (tid >> 3);
    const int og = (tid & 7) * 16;
    const float* Wr = W + f * FOUT + og;
    float s1 = 0.f, s2 = 0.f;
#pragma unroll
    for (int k = 0; k < 16; ++k) {
        const float w = Wr[k];
        s1 += w * a[og + k];
        s2 += w * a[FOUT + og + k];
    }
#pragma unroll
    for (int off = 1; off < 8; off <<= 1) {
        s1 += __shfl_xor(s1, off);
        s2 += __shfl_xor(s2, off);
    }
    if ((tid & 7) == 0) { wa[f] = s1; wa[FIN + f] = s2; }
}

// ---------------- Kernel E: per row n: ei = h.wa1, ej = h.wa2 ----------------
// EE[n] = (exp(ej), exp(0.2 ej), exp(ei), exp(0.2 ei)).  Wave per row.
__global__ __launch_bounds__(256) void k_e(const float* __restrict__ h,
                                           const float* __restrict__ wa,
                                           float4* __restrict__ EE) {
    const int row = blockIdx.x * 4 + (threadIdx.x >> 6);  // 0..16383
    const int lane = threadIdx.x & 63;
    const float4 v = ((const float4*)(h + (size_t)row * FIN))[lane];
    const float4 w1 = ((const float4*)wa)[lane];
    const float4 w2 = ((const float4*)(wa + FIN))[lane];
    float si = v.x * w1.x + v.y * w1.y + v.z * w1.z + v.w * w1.w;
    float sj = v.x * w2.x + v.y * w2.y + v.z * w2.z + v.w * w2.w;
#pragma unroll
    for (int off = 32; off > 0; off >>= 1) {
        si += __shfl_xor(si, off);
        sj += __shfl_xor(sj, off);
    }
    if (lane == 0)
        EE[row] = make_float4(__expf(sj), __expf(0.2f * sj), __expf(si), __expf(0.2f * si));
}

// ---------------- Kernel R: row marginals ----------------
// Per row i: rowsum = Ei1*sum_{ej>=-ei} Ej1 + Ei2*sum_{ej<-ei} Ej2; linv = 1/rowsum.
// UU[i] = (Ei1, Ei1*linv, Ei2*linv, 0).  Wave handles 8 rows; lanes own j-chunks.
__global__ __launch_bounds__(256) void k_row(const float4* __restrict__ EE,
                                             float4* __restrict__ UU) {
    const int wid = blockIdx.x * 4 + (threadIdx.x >> 6);  // 0..2047
    const int lane = threadIdx.x & 63;
    const int i0 = wid * 8;
    const int b = i0 >> 11;
    const float4* EEb = EE + ((size_t)b << 11);

    float rthr[8], ez[8], ew[8];
#pragma unroll
    for (int r = 0; r < 8; ++r) {
        const float4 e = EE[i0 + r];  // uniform load
        ez[r] = e.z; ew[r] = e.w;
        rthr[r] = 1.0f / e.z;         // exp(-ei)
    }
    float s1[8] = {}, s2[8] = {};
    for (int t = 0; t < 32; ++t) {
        const float4 e = EEb[t * 64 + lane];
#pragma unroll
        for (int r = 0; r < 8; ++r) {
            const bool ge = e.x >= rthr[r];  // ei + ej >= 0
            s1[r] += ge ? e.x : 0.f;
            s2[r] += ge ? 0.f : e.y;
        }
    }
#pragma unroll
    for (int r = 0; r < 8; ++r) {
        float a1 = s1[r], a2 = s2[r];
#pragma unroll
        for (int off = 32; off > 0; off >>= 1) {
            a1 += __shfl_xor(a1, off);
            a2 += __shfl_xor(a2, off);
        }
        if (lane == r) {
            const float linv = 1.0f / (ez[r] * a1 + ew[r] * a2);
            UU[i0 + r] = make_float4(ez[r], ez[r] * linv, ew[r] * linv, 0.f);
        }
    }
}

// ---------------- Kernel C: col marginals + g accumulation ----------------
// Per col j: cj = (1/N)(Ej1*sum_{ei>=-ej} u1_i + Ej2*sum_{ei<-ej} u2_i);
// then g[b,:] += cj * h[b,j,:].  Wave handles 8 cols; block reduces to 4 atomics/lane.
__global__ __launch_bounds__(256) void k_col(const float4* __restrict__ EE,
                                             const float4* __restrict__ UU,
                                             const float* __restrict__ h,
                                             float* __restrict__ g) {
    __shared__ float4 gp[4][64];
    const int wv = threadIdx.x >> 6, lane = threadIdx.x & 63;
    const int wid = blockIdx.x * 4 + wv;
    const int j0 = wid * 8;
    const int b = j0 >> 11;
    const float4* UUb = UU + ((size_t)b << 11);

    // prefetch h rows early (T14: issue before the VALU phase)
    float4 hv[8];
#pragma unroll
    for (int r = 0; r < 8; ++r)
        hv[r] = ((const float4*)(h + ((size_t)(j0 + r)) * FIN))[lane];

    float thr[8], ex[8], ey[8];
#pragma unroll
    for (int r = 0; r < 8; ++r) {
        const float4 e = EE[j0 + r];  // uniform load
        ex[r] = e.x; ey[r] = e.y;
        thr[r] = 1.0f / e.x;          // exp(-ej)
    }
    float s1[8] = {}, s2[8] = {};
    for (int t = 0; t < 32; ++t) {
        const float4 u = UUb[t * 64 + lane];  // (Ei1, u1, u2, _)
#pragma unroll
        for (int r = 0; r < 8; ++r) {
            const bool ge = u.x >= thr[r];  // ei + ej >= 0
            s1[r] += ge ? u.y : 0.f;
            s2[r] += ge ? 0.f : u.z;
        }
    }
    float4 gacc = make_float4(0.f, 0.f, 0.f, 0.f);
#pragma unroll
    for (int r = 0; r < 8; ++r) {
        float a1 = s1[r], a2 = s2[r];
#pragma unroll
        for (int off = 32; off > 0; off >>= 1) {
            a1 += __shfl_xor(a1, off);
            a2 += __shfl_xor(a2, off);
        }
        const float cj = (ex[r] * a1 + ey[r] * a2) * (1.0f / NN);
        gacc.x += cj * hv[r].x;
        gacc.y += cj * hv[r].y;
        gacc.z += cj * hv[r].z;
        gacc.w += cj * hv[r].w;
    }
    gp[wv][lane] = gacc;
    __syncthreads();
    if (threadIdx.x < 64) {
        const float4 t0 = gp[0][lane], t1 = gp[1][lane], t2 = gp[2][lane], t3 = gp[3][lane];
        float* gb = g + b * FIN + lane * 4;
        atomicAdd(gb + 0, t0.x + t1.x + t2.x + t3.x);
        atomicAdd(gb + 1, t0.y + t1.y + t2.y + t3.y);
        atomicAdd(gb + 2, t0.z + t1.z + t2.z + t3.z);
        atomicAdd(gb + 3, t0.w + t1.w + t2.w + t3.w);
    }
}

// ---------------- Kernel O: out[b,:] = g[b,:] @ W ----------------
// 32 blocks: (b, f-chunk of 64). Thread: o = tid&127, 32 f's each.
__global__ __launch_bounds__(256) void k_out(const float* __restrict__ g,
                                             const float* __restrict__ W,
                                             float* __restrict__ out) {
    __shared__ float part[2][FOUT];
    const int b = blockIdx.x >> 2;
    const int fc = blockIdx.x & 3;
    const int o = threadIdx.x & 127;
    const int hf = threadIdx.x >> 7;
    const int f0 = fc * 64 + hf * 32;
    float acc = 0.f;
#pragma unroll
    for (int k = 0; k < 32; ++k)
        acc += g[b * FIN + f0 + k] * W[(size_t)(f0 + k) * FOUT + o];
    part[hf][o] = acc;
    __syncthreads();
    if (threadIdx.x < FOUT)
        atomicAdd(&out[b * FOUT + o], part[0][o] + part[1][o]);
}

extern "C" void kernel_launch(void* const* d_in, const int* in_sizes, int n_in,
                              void* d_out, int out_size, void* d_ws, size_t ws_size,
                              hipStream_t stream) {
    const float* h = (const float*)d_in[0];
    const float* W = (const float*)d_in[1];
    const float* a = (const float*)d_in[2];
    float* out = (float*)d_out;

    float4* EE = (float4*)d_ws;                    // 16384 float4
    float4* UU = EE + (size_t)BB * NN;             // 16384 float4
    float* wa = (float*)(UU + (size_t)BB * NN);    // 512 floats
    float* g = wa + 2 * FIN;                       // 2048 floats

    k_prep<<<8, 256, 0, stream>>>(W, a, wa, g, out);
    k_e<<<4096, 256, 0, stream>>>(h, wa, EE);
    k_row<<<512, 256, 0, stream>>>(EE, UU);
    k_col<<<512, 256, 0, stream>>>(EE, UU, h, g);
    k_out<<<32, 256, 0, stream>>>(g, W, out);
}